// Round 1
// baseline (661.829 us; speedup 1.0000x reference)
//
#include <hip/hip_runtime.h>

#define EMB  128
#define HID  64
#define NH   200
#define BT   256
#define LDH1 68    // fp16 LDS stride for H1: 136 B/row (8-B aligned rows, ~2-way banks)

#define WS_FRAG_BYTES 32768   // frag table: 1280 slots * 16 B = 20,480 B used

typedef _Float16 half_t;
typedef half_t half2v __attribute__((ext_vector_type(2)));
typedef half_t half4v __attribute__((ext_vector_type(4)));
typedef half_t half8v __attribute__((ext_vector_type(8)));
typedef float  f32x4  __attribute__((ext_vector_type(4)));

static __device__ __forceinline__ half8v cvt8(float4 a, float4 b) {
    half8v r;
    r[0] = (half_t)a.x; r[1] = (half_t)a.y; r[2] = (half_t)a.z; r[3] = (half_t)a.w;
    r[4] = (half_t)b.x; r[5] = (half_t)b.y; r[6] = (half_t)b.z; r[7] = (half_t)b.w;
    return r;
}

// ---------------------------------------------------------------------------
// Precompute kernel:
//  blocks [0, nblk_c1): c1_all[b][j] = b1[j] + cand[b] @ W1[128:256, j]   (4 b/block)
//  block nblk_c1: MFMA B-fragments of W1a / W2 -> frag_ws.
//    New layout (coalesced for the rewritten main kernel):
//      W1a frag (N-tile nt, k-slice ks) at slot (nt*4+ks)*64 + lane
//      W2  frag (nt, ks)                at slot 1024 + (nt*2+ks)*64 + lane
// ---------------------------------------------------------------------------
__global__ __launch_bounds__(BT) void precomp_kernel(
    const float* __restrict__ W1, const float* __restrict__ b1,
    const float* __restrict__ W2, const float* __restrict__ cand,
    half8v* __restrict__ frag_ws, float* __restrict__ c1_ws, int nblk_c1)
{
    const int tid = threadIdx.x;
    if ((int)blockIdx.x == nblk_c1) {
        const int lane = tid & 63, wid = tid >> 6;
        const int c16 = lane & 15, quad = lane >> 4;
        // W1a B-frags: lane holds B[k = quad*8 + j][n = c16] for N-tile wid
        #pragma unroll
        for (int ks = 0; ks < 4; ++ks) {
            half8v f;
            #pragma unroll
            for (int j = 0; j < 8; ++j)
                f[j] = (half_t)W1[(ks * 32 + quad * 8 + j) * HID + wid * 16 + c16];
            frag_ws[(wid * 4 + ks) * 64 + lane] = f;
        }
        // W2 B-frags (lane-dependent only; one wave stores them)
        if (wid == 0) {
            #pragma unroll
            for (int nt = 0; nt < 2; ++nt)
                #pragma unroll
                for (int ks = 0; ks < 2; ++ks) {
                    half8v f;
                    #pragma unroll
                    for (int j = 0; j < 8; ++j)
                        f[j] = (half_t)W2[(ks * 32 + quad * 8 + j) * (HID / 2) + nt * 16 + c16];
                    frag_ws[1024 + (nt * 2 + ks) * 64 + lane] = f;
                }
        }
    } else {
        __shared__ float W1b_s[EMB * HID];   // 32 KB (W1 rows 128..255)
        __shared__ float cand_s[4 * EMB];
        const int b0 = blockIdx.x * 4;
        {
            const float4* src = (const float4*)(W1 + EMB * HID);
            float4* dst = (float4*)W1b_s;
            for (int i = tid; i < EMB * HID / 4; i += BT) dst[i] = src[i];
            const float4* csrc = (const float4*)(cand + (size_t)b0 * EMB);
            float4* cdst = (float4*)cand_s;
            for (int i = tid; i < EMB; i += BT) cdst[i] = csrc[i];
        }
        __syncthreads();
        const int bl = tid >> 6, j = tid & 63;
        float acc = b1[j];
        #pragma unroll 8
        for (int k = 0; k < EMB; ++k)
            acc = fmaf(cand_s[bl * EMB + k], W1b_s[k * HID + j], acc);
        c1_ws[(size_t)(b0 + bl) * HID + j] = acc;
    }
}

// ---------------------------------------------------------------------------
// Main kernel: one block per batch row b. 4 waves, ~5 blocks/CU (LDS ~30 KB).
// P1: H1 = relu(X@W1a + c1); A-frags loaded DIRECTLY from global (coalesced
//     32 B/lane, full 128-B segments), fp32->fp16 cvt in-register. Wave = N-tile.
// P2: scores = relu(H1@W2 + b2)@W3 via MFMA + shuffle-reduce (M-split).
// P3: masked softmax over 200 (wave 0).
// P4: aggregation re-reads hist from global (L2/LLC-resident by now), float2
//     coalesced, cross-wave reduce through 2-KB LDS scratch.
// ---------------------------------------------------------------------------
__global__ __launch_bounds__(BT, 4) void attn_agg_kernel(
    const float* __restrict__ hist,     // [B, NH, EMB]
    const half8v* __restrict__ frag_ws, // fragment table
    const float* __restrict__ c1_ws,    // [B, HID]
    const float* __restrict__ b2,       // [HID/2]
    const float* __restrict__ W3,       // [HID/2, 1]
    const int*   __restrict__ mask,     // [B, NH]
    float* __restrict__ out_agg,        // [B, EMB]
    float* __restrict__ out_attn)       // [B, NH]
{
    __shared__ __align__(16) half_t H1_s[NH * LDH1];  // 27,200 B
    __shared__ float attn_s[NH];
    __shared__ float2 red_s[BT];                      // 2 KB
    // total ~30.1 KB -> 5 blocks/CU

    const int b    = blockIdx.x;
    const int tid  = threadIdx.x;
    const int lane = tid & 63;
    const int wid  = tid >> 6;
    const int c16  = lane & 15;
    const int quad = lane >> 4;

    const float* hb = hist + (size_t)b * (NH * EMB);

    // ---- W1 fragments for this wave's N-tile (coalesced, L2-resident) ----
    half8v w1f[4];
    #pragma unroll
    for (int ks = 0; ks < 4; ++ks)
        w1f[ks] = frag_ws[(wid * 4 + ks) * 64 + lane];

    const float c1v = c1_ws[(size_t)b * HID + wid * 16 + c16];

    // ---- P1: H1 = relu(X @ W1a + c1), A-frags straight from global ----
    for (int t = 0; t < 13; ++t) {
        const int m0 = (t < 12) ? t * 16 : 184;
        const float* rp = hb + (m0 + c16) * EMB + quad * 8;
        float4 x0a = *(const float4*)(rp);
        float4 x0b = *(const float4*)(rp + 4);
        float4 x1a = *(const float4*)(rp + 32);
        float4 x1b = *(const float4*)(rp + 36);
        float4 x2a = *(const float4*)(rp + 64);
        float4 x2b = *(const float4*)(rp + 68);
        float4 x3a = *(const float4*)(rp + 96);
        float4 x3b = *(const float4*)(rp + 100);
        f32x4 acc = {0.f, 0.f, 0.f, 0.f};
        acc = __builtin_amdgcn_mfma_f32_16x16x32_f16(cvt8(x0a, x0b), w1f[0], acc, 0, 0, 0);
        acc = __builtin_amdgcn_mfma_f32_16x16x32_f16(cvt8(x1a, x1b), w1f[1], acc, 0, 0, 0);
        acc = __builtin_amdgcn_mfma_f32_16x16x32_f16(cvt8(x2a, x2b), w1f[2], acc, 0, 0, 0);
        acc = __builtin_amdgcn_mfma_f32_16x16x32_f16(cvt8(x3a, x3b), w1f[3], acc, 0, 0, 0);
        #pragma unroll
        for (int i = 0; i < 4; ++i) {
            int r = m0 + 4 * quad + i;
            // banks: (34r + 8n + c16/2) -> c16 pairs 2/bank (free), quad spreads octets
            H1_s[r * LDH1 + wid * 16 + c16] = (half_t)fmaxf(acc[i] + c1v, 0.f);
        }
    }
    __syncthreads();

    // ---- P2: scores, M-tiles split across waves ----
    half8v w2f[2][2];
    w2f[0][0] = frag_ws[1024 + 0 * 64 + lane];
    w2f[0][1] = frag_ws[1024 + 1 * 64 + lane];
    w2f[1][0] = frag_ws[1024 + 2 * 64 + lane];
    w2f[1][1] = frag_ws[1024 + 3 * 64 + lane];
    const float w3a  = W3[c16];
    const float w3b  = W3[16 + c16];
    const float bb2a = b2[c16];
    const float bb2b = b2[16 + c16];

    for (int t = wid; t < 13; t += 4) {
        const int m0 = (t < 12) ? t * 16 : 184;
        const int row = m0 + c16;
        f32x4 acc0 = {0.f, 0.f, 0.f, 0.f};
        f32x4 acc1 = {0.f, 0.f, 0.f, 0.f};
        #pragma unroll
        for (int ks = 0; ks < 2; ++ks) {
            const half_t* ap = &H1_s[row * LDH1 + ks * 32 + quad * 8];
            half4v alo = *(const half4v*)ap;
            half4v ahi = *(const half4v*)(ap + 4);
            half8v a = __builtin_shufflevector(alo, ahi, 0, 1, 2, 3, 4, 5, 6, 7);
            acc0 = __builtin_amdgcn_mfma_f32_16x16x32_f16(a, w2f[0][ks], acc0, 0, 0, 0);
            acc1 = __builtin_amdgcn_mfma_f32_16x16x32_f16(a, w2f[1][ks], acc1, 0, 0, 0);
        }
        float sp[4];
        #pragma unroll
        for (int i = 0; i < 4; ++i)
            sp[i] = fmaxf(acc0[i] + bb2a, 0.f) * w3a + fmaxf(acc1[i] + bb2b, 0.f) * w3b;
        #pragma unroll
        for (int m = 1; m < 16; m <<= 1)
            #pragma unroll
            for (int i = 0; i < 4; ++i)
                sp[i] += __shfl_xor(sp[i], m, 64);
        if (c16 == 0) {
            const int lo = (t == 12) ? 192 : m0;   // skip dup rows 184..191
            #pragma unroll
            for (int i = 0; i < 4; ++i) {
                int r = m0 + 4 * quad + i;
                if (r >= lo) attn_s[r] = sp[i];
            }
        }
    }
    __syncthreads();

    // ---- P3: masked softmax over 200 (wave 0) ----
    if (tid < 64) {
        const int* mb = mask + (size_t)b * NH;
        float s0 = attn_s[tid]       + (1.f - (float)mb[tid])       * -1e9f;
        float s1 = attn_s[64 + tid]  + (1.f - (float)mb[64 + tid])  * -1e9f;
        float s2 = attn_s[128 + tid] + (1.f - (float)mb[128 + tid]) * -1e9f;
        float s3 = (tid < 8) ? attn_s[192 + tid] + (1.f - (float)mb[192 + tid]) * -1e9f : -1e30f;
        float m = fmaxf(fmaxf(s0, s1), fmaxf(s2, s3));
        #pragma unroll
        for (int off = 32; off; off >>= 1) m = fmaxf(m, __shfl_xor(m, off, 64));
        float e0 = __expf(s0 - m);
        float e1 = __expf(s1 - m);
        float e2 = __expf(s2 - m);
        float e3 = (tid < 8) ? __expf(s3 - m) : 0.f;
        float sum = e0 + e1 + e2 + e3;
        #pragma unroll
        for (int off = 32; off; off >>= 1) sum += __shfl_xor(sum, off, 64);
        float inv = 1.f / sum;
        e0 *= inv; e1 *= inv; e2 *= inv; e3 *= inv;
        attn_s[tid] = e0; attn_s[64 + tid] = e1; attn_s[128 + tid] = e2;
        if (tid < 8) attn_s[192 + tid] = e3;
        float* oa = out_attn + (size_t)b * NH;
        oa[tid] = e0; oa[64 + tid] = e1; oa[128 + tid] = e2;
        if (tid < 8) oa[192 + tid] = e3;
    }
    __syncthreads();

    // ---- P4: aggregation, re-read hist from global (L2/LLC-warm), float2 ----
    {
        const int c = tid & 63;
        const int g = wid;
        float2 acc = make_float2(0.f, 0.f);
        const float* xp = hb + g * 50 * EMB + 2 * c;
        #pragma unroll 5
        for (int h = 0; h < 50; ++h) {
            float w = attn_s[g * 50 + h];
            float2 v = *(const float2*)(xp + (size_t)h * EMB);
            acc.x = fmaf(w, v.x, acc.x);
            acc.y = fmaf(w, v.y, acc.y);
        }
        red_s[tid] = acc;
        __syncthreads();
        if (tid < 64) {
            float2 r0 = red_s[tid], r1 = red_s[64 + tid], r2 = red_s[128 + tid], r3 = red_s[192 + tid];
            float2 o = make_float2(r0.x + r1.x + r2.x + r3.x,
                                   r0.y + r1.y + r2.y + r3.y);
            *(float2*)&out_agg[(size_t)b * EMB + tid * 2] = o;
        }
    }
}

extern "C" void kernel_launch(void* const* d_in, const int* in_sizes, int n_in,
                              void* d_out, int out_size, void* d_ws, size_t ws_size,
                              hipStream_t stream) {
    const float* hist = (const float*)d_in[0];
    const float* cand = (const float*)d_in[1];
    const float* W1   = (const float*)d_in[2];
    const float* b1   = (const float*)d_in[3];
    const float* W2   = (const float*)d_in[4];
    const float* b2   = (const float*)d_in[5];
    const float* W3   = (const float*)d_in[6];
    const int*   mask = (const int*)d_in[8];

    const int B = in_sizes[0] / (NH * EMB * 4);   // bytes -> rows? (see note below)
    // in_sizes is element-count based in this harness (prior session used /(NH*EMB));
    // keep identical semantics to the verified kernel:
    const int Brows = in_sizes[0] / (NH * EMB);
    (void)B;

    float* out_agg  = (float*)d_out;                  // [B, EMB]
    float* out_attn = out_agg + (size_t)Brows * EMB;  // [B, NH]

    half8v* frag_ws = (half8v*)d_ws;
    float*  c1_ws   = (float*)((char*)d_ws + WS_FRAG_BYTES);

    const int nblk_c1 = Brows / 4;
    precomp_kernel<<<nblk_c1 + 1, BT, 0, stream>>>(W1, b1, W2, cand, frag_ws, c1_ws, nblk_c1);
    attn_agg_kernel<<<Brows, BT, 0, stream>>>(hist, frag_ws, c1_ws, b2, W3, mask,
                                              out_agg, out_attn);
}

// Round 2
// 622.642 us; speedup vs baseline: 1.0629x; 1.0629x over previous
//
#include <hip/hip_runtime.h>

#define EMB  128
#define HID  64
#define NH   200
#define BT   256
#define LDX  132   // fp16 LDS stride for X rows: 264 B (proven layout from round-0)
#define LDH1 68    // fp16 LDS stride for H1 rows: 136 B

#define WS_FRAG_BYTES 32768
#define WS_C1_BYTES   (1u << 20)   // 4096 * 64 * 4

typedef _Float16 half_t;
typedef half_t half2v __attribute__((ext_vector_type(2)));
typedef half_t half4v __attribute__((ext_vector_type(4)));
typedef half_t half8v __attribute__((ext_vector_type(8)));
typedef float  f32x4  __attribute__((ext_vector_type(4)));

// ---------------------------------------------------------------------------
// Precompute kernel (unchanged math from verified round-0/1):
//  blocks [0, nblk_c1): c1_ws[b][j] = b1[j] + cand[b] @ W1[128:256, j]
//  block nblk_c1: MFMA B-fragments of W1a / W2 -> frag_ws
//      W1a frag (N-tile nt, k-slice ks) at slot (nt*4+ks)*64 + lane
//      W2  frag (nt, ks)               at slot 1024 + (nt*2+ks)*64 + lane
// ---------------------------------------------------------------------------
__global__ __launch_bounds__(BT) void precomp_kernel(
    const float* __restrict__ W1, const float* __restrict__ b1,
    const float* __restrict__ W2, const float* __restrict__ cand,
    half8v* __restrict__ frag_ws, float* __restrict__ c1_ws, int nblk_c1)
{
    const int tid = threadIdx.x;
    if ((int)blockIdx.x == nblk_c1) {
        const int lane = tid & 63, wid = tid >> 6;
        const int c16 = lane & 15, quad = lane >> 4;
        #pragma unroll
        for (int ks = 0; ks < 4; ++ks) {
            half8v f;
            #pragma unroll
            for (int j = 0; j < 8; ++j)
                f[j] = (half_t)W1[(ks * 32 + quad * 8 + j) * HID + wid * 16 + c16];
            frag_ws[(wid * 4 + ks) * 64 + lane] = f;
        }
        if (wid == 0) {
            #pragma unroll
            for (int nt = 0; nt < 2; ++nt)
                #pragma unroll
                for (int ks = 0; ks < 2; ++ks) {
                    half8v f;
                    #pragma unroll
                    for (int j = 0; j < 8; ++j)
                        f[j] = (half_t)W2[(ks * 32 + quad * 8 + j) * (HID / 2) + nt * 16 + c16];
                    frag_ws[1024 + (nt * 2 + ks) * 64 + lane] = f;
                }
        }
    } else {
        __shared__ float W1b_s[EMB * HID];   // 32 KB (W1 rows 128..255)
        __shared__ float cand_s[4 * EMB];
        const int b0 = blockIdx.x * 4;
        {
            const float4* src = (const float4*)(W1 + EMB * HID);
            float4* dst = (float4*)W1b_s;
            for (int i = tid; i < EMB * HID / 4; i += BT) dst[i] = src[i];
            const float4* csrc = (const float4*)(cand + (size_t)b0 * EMB);
            float4* cdst = (float4*)cand_s;
            for (int i = tid; i < EMB; i += BT) cdst[i] = csrc[i];
        }
        __syncthreads();
        const int bl = tid >> 6, j = tid & 63;
        float acc = b1[j];
        #pragma unroll 8
        for (int k = 0; k < EMB; ++k)
            acc = fmaf(cand_s[bl * EMB + k], W1b_s[k * HID + j], acc);
        c1_ws[(size_t)(b0 + bl) * HID + j] = acc;
    }
}

// ---------------------------------------------------------------------------
// K1: scores over flattened M = B*NH. 64 rows/block, 12800 blocks,
// LDS ~26 KB -> 6 blocks/CU. Stage fp32->fp16 LDS (coalesced), MFMA
// layer1 (wave = N-tile), MFMA layer2+W3 dot (wave = M-tile), write raw
// scores to ws. b3 omitted (softmax shift-invariant, masked rows dominated
// by -1e9 regardless).
// ---------------------------------------------------------------------------
__global__ __launch_bounds__(BT, 4) void scores_kernel(
    const float* __restrict__ hist,     // [B*NH, EMB]
    const half8v* __restrict__ frag_ws,
    const float* __restrict__ c1_ws,    // [B, HID]
    const float* __restrict__ b2,       // [HID/2]
    const float* __restrict__ W3,       // [HID/2]
    float* __restrict__ scores_ws)      // [B*NH]
{
    __shared__ __align__(16) half_t X_s[64 * LDX];    // 16,896 B
    __shared__ __align__(16) half_t H1_s[64 * LDH1];  //  8,704 B
    __shared__ float c1a_s[HID], c1b_s[HID];

    const int tid  = threadIdx.x;
    const int lane = tid & 63;
    const int wid  = tid >> 6;
    const int c16  = lane & 15;
    const int quad = lane >> 4;

    const int r0  = blockIdx.x * 64;        // first global row of this tile
    const int b0r = r0 / 200;               // tile spans <= 2 batch rows
    const int b1r = (r0 + 63) / 200;
    const int thr = (b0r + 1) * 200;        // rows >= thr belong to b1r

    if (tid < HID)            c1a_s[tid]       = c1_ws[(size_t)b0r * HID + tid];
    else if (tid < 2 * HID)   c1b_s[tid - HID] = c1_ws[(size_t)b1r * HID + (tid - HID)];

    half8v w1f[4];
    #pragma unroll
    for (int ks = 0; ks < 4; ++ks)
        w1f[ks] = frag_ws[(wid * 4 + ks) * 64 + lane];

    // ---- stage 64 rows fp32 -> fp16 LDS (8 float4/thread, coalesced) ----
    {
        const float4* src = (const float4*)(hist + (size_t)r0 * EMB);
        #pragma unroll
        for (int t = 0; t < 8; ++t) {
            int i = t * BT + tid;
            int h = i >> 5, c4 = i & 31;
            float4 v = src[i];
            half2v p0 = {(half_t)v.x, (half_t)v.y};
            half2v p1 = {(half_t)v.z, (half_t)v.w};
            *(half2v*)&X_s[h * LDX + c4 * 4]     = p0;
            *(half2v*)&X_s[h * LDX + c4 * 4 + 2] = p1;
        }
    }
    __syncthreads();

    // ---- layer 1: H1 = relu(X @ W1a + c1), wave = N-tile ----
    {
        const float c1va = c1a_s[wid * 16 + c16];
        const float c1vb = c1b_s[wid * 16 + c16];
        #pragma unroll
        for (int t = 0; t < 4; ++t) {
            const int m0 = t * 16;
            const int row = m0 + c16;
            f32x4 acc = {0.f, 0.f, 0.f, 0.f};
            #pragma unroll
            for (int ks = 0; ks < 4; ++ks) {
                const half_t* ap = &X_s[row * LDX + ks * 32 + quad * 8];
                half4v alo = *(const half4v*)ap;
                half4v ahi = *(const half4v*)(ap + 4);
                half8v a = __builtin_shufflevector(alo, ahi, 0, 1, 2, 3, 4, 5, 6, 7);
                acc = __builtin_amdgcn_mfma_f32_16x16x32_f16(a, w1f[ks], acc, 0, 0, 0);
            }
            #pragma unroll
            for (int i = 0; i < 4; ++i) {
                int rr = m0 + 4 * quad + i;
                float c1v = (r0 + rr < thr) ? c1va : c1vb;
                H1_s[rr * LDH1 + wid * 16 + c16] = (half_t)fmaxf(acc[i] + c1v, 0.f);
            }
        }
    }
    __syncthreads();

    // ---- layer 2 + 3: wave wid handles rows [wid*16, wid*16+16) ----
    {
        half8v w2f[2][2];
        w2f[0][0] = frag_ws[1024 + 0 * 64 + lane];
        w2f[0][1] = frag_ws[1024 + 1 * 64 + lane];
        w2f[1][0] = frag_ws[1024 + 2 * 64 + lane];
        w2f[1][1] = frag_ws[1024 + 3 * 64 + lane];
        const float w3a  = W3[c16];
        const float w3b  = W3[16 + c16];
        const float bb2a = b2[c16];
        const float bb2b = b2[16 + c16];

        const int m0 = wid * 16;
        const int row = m0 + c16;
        f32x4 acc0 = {0.f, 0.f, 0.f, 0.f};
        f32x4 acc1 = {0.f, 0.f, 0.f, 0.f};
        #pragma unroll
        for (int ks = 0; ks < 2; ++ks) {
            const half_t* ap = &H1_s[row * LDH1 + ks * 32 + quad * 8];
            half4v alo = *(const half4v*)ap;
            half4v ahi = *(const half4v*)(ap + 4);
            half8v a = __builtin_shufflevector(alo, ahi, 0, 1, 2, 3, 4, 5, 6, 7);
            acc0 = __builtin_amdgcn_mfma_f32_16x16x32_f16(a, w2f[0][ks], acc0, 0, 0, 0);
            acc1 = __builtin_amdgcn_mfma_f32_16x16x32_f16(a, w2f[1][ks], acc1, 0, 0, 0);
        }
        float sp[4];
        #pragma unroll
        for (int i = 0; i < 4; ++i)
            sp[i] = fmaxf(acc0[i] + bb2a, 0.f) * w3a + fmaxf(acc1[i] + bb2b, 0.f) * w3b;
        #pragma unroll
        for (int m = 1; m < 16; m <<= 1)
            #pragma unroll
            for (int i = 0; i < 4; ++i)
                sp[i] += __shfl_xor(sp[i], m, 64);
        if (c16 == 0) {
            #pragma unroll
            for (int i = 0; i < 4; ++i)
                scores_ws[(size_t)r0 + m0 + 4 * quad + i] = sp[i];
        }
    }
}

// ---------------------------------------------------------------------------
// K2: one block per b (grid reversed so first blocks read the LLC-warm tail
// of K1's stream). Wave-0 masked softmax from ws scores; aggregation streams
// hist as float4 (2 rows / wave-instruction, fully coalesced). LDS ~5 KB ->
// 8 blocks/CU (thread-cap).
// ---------------------------------------------------------------------------
__global__ __launch_bounds__(BT, 8) void softmax_agg_kernel(
    const float* __restrict__ hist,      // [B, NH, EMB]
    const float* __restrict__ scores_ws, // [B, NH]
    const int*   __restrict__ mask,      // [B, NH]
    float* __restrict__ out_agg,         // [B, EMB]
    float* __restrict__ out_attn,        // [B, NH]
    int Bn)
{
    __shared__ float attn_s[NH];
    __shared__ __align__(16) f32x4 red_s[BT];   // 4 KB

    const int tid = threadIdx.x;
    const int b = Bn - 1 - (int)blockIdx.x;

    // ---- masked softmax over 200 (wave 0) ----
    if (tid < 64) {
        const float* sc = scores_ws + (size_t)b * NH;
        const int* mb = mask + (size_t)b * NH;
        float s0 = sc[tid]       + (1.f - (float)mb[tid])       * -1e9f;
        float s1 = sc[64 + tid]  + (1.f - (float)mb[64 + tid])  * -1e9f;
        float s2 = sc[128 + tid] + (1.f - (float)mb[128 + tid]) * -1e9f;
        float s3 = (tid < 8) ? sc[192 + tid] + (1.f - (float)mb[192 + tid]) * -1e9f : -1e30f;
        float m = fmaxf(fmaxf(s0, s1), fmaxf(s2, s3));
        #pragma unroll
        for (int off = 32; off; off >>= 1) m = fmaxf(m, __shfl_xor(m, off, 64));
        float e0 = __expf(s0 - m);
        float e1 = __expf(s1 - m);
        float e2 = __expf(s2 - m);
        float e3 = (tid < 8) ? __expf(s3 - m) : 0.f;
        float sum = e0 + e1 + e2 + e3;
        #pragma unroll
        for (int off = 32; off; off >>= 1) sum += __shfl_xor(sum, off, 64);
        float inv = 1.f / sum;
        e0 *= inv; e1 *= inv; e2 *= inv; e3 *= inv;
        attn_s[tid] = e0; attn_s[64 + tid] = e1; attn_s[128 + tid] = e2;
        if (tid < 8) attn_s[192 + tid] = e3;
        float* oa = out_attn + (size_t)b * NH;
        oa[tid] = e0; oa[64 + tid] = e1; oa[128 + tid] = e2;
        if (tid < 8) oa[192 + tid] = e3;
    }
    __syncthreads();

    // ---- aggregation: float4 streaming, wave g covers rows [50g, 50g+50) ----
    {
        const int c   = tid & 63;
        const int g   = tid >> 6;
        const int h2  = c >> 5;      // 0/1: which of the 2 rows this lane covers
        const int c32 = c & 31;      // float4 index within the row
        const float4* hp = (const float4*)(hist + (size_t)b * NH * EMB);
        f32x4 acc = {0.f, 0.f, 0.f, 0.f};
        #pragma unroll 5
        for (int j = 0; j < 25; ++j) {
            int h = g * 50 + 2 * j + h2;
            float w = attn_s[h];
            float4 v = hp[h * 32 + c32];
            acc[0] = fmaf(w, v.x, acc[0]);
            acc[1] = fmaf(w, v.y, acc[1]);
            acc[2] = fmaf(w, v.z, acc[2]);
            acc[3] = fmaf(w, v.w, acc[3]);
        }
        red_s[tid] = acc;
        __syncthreads();
        if (tid < 32) {
            f32x4 o = red_s[tid];
            #pragma unroll
            for (int k = 1; k < 8; ++k) {
                f32x4 r = red_s[k * 32 + tid];
                o[0] += r[0]; o[1] += r[1]; o[2] += r[2]; o[3] += r[3];
            }
            *(f32x4*)&out_agg[(size_t)b * EMB + tid * 4] = o;
        }
    }
}

extern "C" void kernel_launch(void* const* d_in, const int* in_sizes, int n_in,
                              void* d_out, int out_size, void* d_ws, size_t ws_size,
                              hipStream_t stream) {
    const float* hist = (const float*)d_in[0];
    const float* cand = (const float*)d_in[1];
    const float* W1   = (const float*)d_in[2];
    const float* b1   = (const float*)d_in[3];
    const float* W2   = (const float*)d_in[4];
    const float* b2   = (const float*)d_in[5];
    const float* W3   = (const float*)d_in[6];
    const int*   mask = (const int*)d_in[8];

    const int Brows = in_sizes[0] / (NH * EMB);   // 4096

    float* out_agg  = (float*)d_out;                  // [B, EMB]
    float* out_attn = out_agg + (size_t)Brows * EMB;  // [B, NH]

    half8v* frag_ws   = (half8v*)d_ws;
    float*  c1_ws     = (float*)((char*)d_ws + WS_FRAG_BYTES);
    float*  scores_ws = (float*)((char*)d_ws + WS_FRAG_BYTES + WS_C1_BYTES);

    const int nblk_c1 = Brows / 4;
    precomp_kernel<<<nblk_c1 + 1, BT, 0, stream>>>(W1, b1, W2, cand, frag_ws, c1_ws, nblk_c1);

    const int nblk_scores = (Brows * NH) / 64;    // 12800
    scores_kernel<<<nblk_scores, BT, 0, stream>>>(hist, frag_ws, c1_ws, b2, W3, scores_ws);

    softmax_agg_kernel<<<Brows, BT, 0, stream>>>(hist, scores_ws, mask,
                                                 out_agg, out_attn, Brows);
}